// Round 11
// baseline (72198.718 us; speedup 1.0000x reference)
//
#include <hip/hip_runtime.h>

// LIIFParametric3DConv — round 11: f32 INPUTS -> f32 OUTPUT (the real fix).
// R10's invisible spike proved the output buffer is float32: all prior rounds
// wrote bf16 u16s into it, so the checker compared our pixel 2i+1 against ref
// pixel i — full decorrelation even for a correct pipeline. This round is the
// R8 pipeline (doc-order inputs, correlation conv per JAX, floor/ceil gather,
// scalar-VALU SIREN MLP, lerp) emitting float32.
//
// ws layout (bytes):
//   feat  @ 0          : 150,994,944  (589824 rows x 64 ch f32 conv features)
//   preds @ 150994944  : 4,718,592    (1,179,648 f32: eval = pixel*2 + fc)
//   total 155,713,536  (fits: R7-R9 ran with the same footprint)

using s16x8 = __attribute__((ext_vector_type(8))) short;
using s16x4 = __attribute__((ext_vector_type(4))) short;

__device__ __forceinline__ float bf2f(unsigned short u){
  return __uint_as_float(((unsigned)u) << 16);
}
__device__ __forceinline__ short f2bf(float f){
  unsigned b = __float_as_uint(f);
  return (short)((b + 0x7FFFu + ((b >> 16) & 1u)) >> 16);
}

// ---------------- conv3d 2->64, 3x3x3, SAME (cross-correlation, as JAX) -----
__global__ __launch_bounds__(256) void conv_kernel(
    const float* __restrict__ xr, const float* __restrict__ xi,
    const float* __restrict__ enc_w, const float* __restrict__ enc_b,
    float* __restrict__ feat)
{
  __shared__ __align__(16) float wl[64][56];  // 54 taps + 2 pad per channel
  __shared__ float bl[64];
  const int tid = threadIdx.x;
  for(int i=tid;i<3456;i+=256) wl[i/54][i%54] = enc_w[i];
  if(tid<128) wl[tid>>1][54+(tid&1)] = 0.f;
  if(tid<64)  bl[tid] = enc_b[tid];
  __syncthreads();

  const unsigned bi   = blockIdx.x;          // 2304 = 2*32*36
  const unsigned tile = bi % 36u;
  const unsigned t    = (bi/36u) % 32u;
  const unsigned b    = bi / 1152u;
  const int h = (int)((tile/6u)*16u) + (tid>>4);
  const int w = (int)((tile%6u)*16u) + (tid&15);

  float xv[56];
  xv[54]=0.f; xv[55]=0.f;
  int k=0;
  #pragma unroll
  for(int i=0;i<2;i++){
    const float* src = i ? xi : xr;
    #pragma unroll
    for(int dz=-1;dz<=1;dz++){
      const int tt = (int)t + dz;
      const bool tok = (tt>=0 && tt<32);
      const size_t tbase = (size_t)(b*32u + (unsigned)(tok?tt:0))*9216u;
      #pragma unroll
      for(int dy=-1;dy<=1;dy++){
        const int hh = h+dy;
        const bool hok = (hh>=0 && hh<96);
        #pragma unroll
        for(int dx=-1;dx<=1;dx++){
          const int ww = w+dx;
          const bool ok = tok && hok && (ww>=0 && ww<96);
          xv[k] = ok ? src[tbase + (size_t)(hh*96+ww)] : 0.f;
          k++;
        }
      }
    }
  }

  const unsigned idx = (b*32u+t)*9216u + (unsigned)(h*96+w);
  float* pf = feat + (size_t)idx*64u;
  #pragma unroll
  for(int g=0; g<16; g++){   // 16 groups of 4 channels -> float4 stores
    float4 o;
    #pragma unroll
    for(int c4=0;c4<4;c4++){
      const int c = g*4 + c4;
      float acc = bl[c];
      const float4* wp = (const float4*)(&wl[c][0]);
      #pragma unroll
      for(int qq=0;qq<14;qq++){
        const float4 w4 = wp[qq];
        acc += w4.x*xv[qq*4+0] + w4.y*xv[qq*4+1]
             + w4.z*xv[qq*4+2] + w4.w*xv[qq*4+3];
      }
      ((float*)&o)[c4] = acc;
    }
    ((float4*)pf)[g] = o;
  }
}

// ---------------- scalar-VALU SIREN MLP, 64 evals per 256-thread block ------
// Phase 0: meta + feat[65][64] f32 in LDS
// Phase 1: thread t = neuron n: h1[n][e] = sin(30*(feat@W1col_n + b1)), bf16 LDS
// Phase 2: thread t = neuron n: z2[e] = sum_k h1[k][e]*W2[k][n]
// Phase 3: contrib = sin(30*(z2+b2))*W3[n], 4-pass LDS transpose reduction
__global__ __launch_bounds__(256) void mlp_kernel(
  const float* __restrict__ tcoord, const float* __restrict__ feat,
  const float* __restrict__ W1, const float* __restrict__ b1,
  const float* __restrict__ W2, const float* __restrict__ b2,
  const float* __restrict__ W3, float* __restrict__ preds)
{
  __shared__ __align__(16) float fr[4160];       // feat[k][e] = fr[k*64+e]
  __shared__ __align__(16) short h1s[256][72];
  __shared__ unsigned evoff[64];

  const int t = threadIdx.x;
  const unsigned evb = blockIdx.x * 64u;

  if(t < 64){
    const unsigned ev = evb + (unsigned)t;
    const unsigned pt = ev>>1;
    const unsigned fc = ev&1u;
    const unsigned wq = pt%96u;
    const unsigned hq = (pt/96u)%96u;
    const unsigned jq = (pt/9216u)%32u;
    const unsigned bq = pt/294912u;
    float tc = tcoord[bq*32u+jq];
    tc = fminf(fmaxf(tc, -1.0f), 1.0f - 1e-6f);
    const float dstep = 2.0f/31.0f;
    const int ti = (int)floorf((tc+1.0f)/dstep);
    const unsigned trow = (unsigned)ti + fc;       // <= 31
    evoff[t] = (bq*32u+trow)*9216u + hq*96u + wq;
    fr[64*64 + t] = tc;                            // feat[64][e] = tc
  }
  __syncthreads();

  { // phase 0b: features f32 -> feat[k][e]
    const int e    = t>>2;
    const int part = t&3;
    const float* src = feat + (size_t)evoff[e]*64u + (size_t)part*16u;
    #pragma unroll
    for(int j=0;j<4;j++){
      const float4 v = ((const float4*)src)[j];
      const int c0 = part*16 + j*4;
      fr[(c0+0)*64 + e] = v.x;
      fr[(c0+1)*64 + e] = v.y;
      fr[(c0+2)*64 + e] = v.z;
      fr[(c0+3)*64 + e] = v.w;
    }
  }
  __syncthreads();

  { // phase 1: layer 1, neuron n = t
    float w1r[65];
    #pragma unroll
    for(int k=0;k<65;k++) w1r[k] = W1[(size_t)k*256 + t];
    const float b1v = b1[t];
    #pragma unroll 1
    for(int e4=0; e4<16; e4++){
      float zx=b1v, zy=b1v, zz=b1v, zw=b1v;
      #pragma unroll
      for(int k=0;k<65;k++){
        const float4 f = *(const float4*)(&fr[k*64 + e4*4]);
        zx += f.x*w1r[k]; zy += f.y*w1r[k];
        zz += f.z*w1r[k]; zw += f.w*w1r[k];
      }
      s16x4 hq4;
      hq4[0] = f2bf(sinf(30.0f*zx));
      hq4[1] = f2bf(sinf(30.0f*zy));
      hq4[2] = f2bf(sinf(30.0f*zz));
      hq4[3] = f2bf(sinf(30.0f*zw));
      *(s16x4*)(&h1s[t][e4*4]) = hq4;
    }
  }
  __syncthreads();

  // phase 2: layer 2, neuron n = t
  float z2[64];
  #pragma unroll
  for(int e=0;e<64;e++) z2[e] = 0.f;
  #pragma unroll 1
  for(int kb=0; kb<8; kb++){
    float w2r[32];
    #pragma unroll
    for(int kk=0;kk<32;kk++) w2r[kk] = W2[(size_t)(kb*32+kk)*256 + t];
    #pragma unroll
    for(int kk=0;kk<32;kk++){
      const int k = kb*32 + kk;
      #pragma unroll
      for(int e8=0; e8<8; e8++){
        const s16x8 hq8 = *(const s16x8*)(&h1s[k][e8*8]);
        #pragma unroll
        for(int i=0;i<8;i++)
          z2[e8*8+i] += bf2f((unsigned short)hq8[i]) * w2r[kk];
      }
    }
  }

  { // phase 3: sin + W3 weight
    const float b2v = b2[t];
    const float w3v = W3[t];
    #pragma unroll
    for(int e=0;e<64;e++)
      z2[e] = sinf(30.0f*(z2[e] + b2v)) * w3v;
  }
  __syncthreads();   // fr dead; reuse as red[e*65 + col]
  float s = 0.f;
  #pragma unroll 1
  for(int p=0;p<4;p++){
    if((t>>6)==p){
      #pragma unroll
      for(int e=0;e<64;e++) fr[e*65 + (t&63)] = z2[e];
    }
    __syncthreads();
    if(t<64){
      #pragma unroll
      for(int i=0;i<64;i++) s += fr[t*65 + i];
    }
    __syncthreads();
  }
  if(t<64) preds[evb + (unsigned)t] = s;
}

// ---------------- lerp + b3 + f32 store -------------------------------------
__global__ __launch_bounds__(256) void lerp_kernel(
  const float* __restrict__ preds, const float* __restrict__ tcoord,
  const float* __restrict__ b3, float* __restrict__ out, unsigned n)
{
  const unsigned p = blockIdx.x*256u + threadIdx.x;
  if(p >= n) return;
  const float2 pr = ((const float2*)preds)[p];
  const unsigned jq = (p/9216u)%32u;
  const unsigned bq = p/294912u;
  float tc = tcoord[bq*32u+jq];
  tc = fminf(fmaxf(tc, -1.0f), 1.0f - 1e-6f);
  const float dstep = 2.0f/31.0f;
  const int ti = (int)floorf((tc+1.0f)/dstep);
  const float fci = (float)((double)ti*(2.0/31.0) - 1.0);  // linspace value
  const float tau = (tc - fci)/dstep;
  out[p] = pr.x*(1.0f-tau) + pr.y*tau + b3[0];
}

extern "C" void kernel_launch(void* const* d_in, const int* in_sizes, int n_in,
                              void* d_out, int out_size, void* d_ws, size_t ws_size,
                              hipStream_t stream){
  const float* xr     = (const float*)d_in[0];
  const float* xi     = (const float*)d_in[1];
  const float* tcoord = (const float*)d_in[2];
  const float* enc_w  = (const float*)d_in[3];
  const float* enc_b  = (const float*)d_in[4];
  const float* W1     = (const float*)d_in[5];
  const float* b1     = (const float*)d_in[6];
  const float* W2     = (const float*)d_in[7];
  const float* b2     = (const float*)d_in[8];
  const float* W3     = (const float*)d_in[9];
  const float* b3     = (const float*)d_in[10];

  char* ws = (char*)d_ws;
  float* feat  = (float*)(ws);
  float* preds = (float*)(ws + 150994944);
  float* out   = (float*)d_out;
  const unsigned nout = (unsigned)out_size;   // 589824

  hipLaunchKernelGGL(conv_kernel, dim3(2304),  dim3(256), 0, stream,
                     xr, xi, enc_w, enc_b, feat);
  hipLaunchKernelGGL(mlp_kernel,  dim3(18432), dim3(256), 0, stream,
                     tcoord, feat, W1, b1, W2, b2, W3, preds);
  hipLaunchKernelGGL(lerp_kernel, dim3((nout+255u)/256u), dim3(256), 0, stream,
                     preds, tcoord, b3, out, nout);
}

// Round 12
// 1088.083 us; speedup vs baseline: 66.3540x; 66.3540x over previous
//
#include <hip/hip_runtime.h>

// LIIFParametric3DConv — round 12: MFMA SIREN MLP (f32 in / f32 out).
// R11 passed (scalar, absmax 9.77e-4) but mlp spilled ~93 GB scratch/dispatch
// (VALUBusy 6%). This round: conv emits bf16 hi/lo feature rows; MLP uses
// mfma_f32_16x16x32_bf16 with W1 hi+lo (layer-1 at ~fp32 accuracy), h1
// round-trips XOR-swizzled LDS, layer-2 B-frags from L2-resident W2T, and the
// temporal lerp is fused into the epilogue (no preds buffer, no lerp kernel).
//
// ws layout (bytes):
//   fhi  @ 0          : 75,497,472  (589824 rows x 64ch bf16, hi)
//   flo  @ 75497472   : 75,497,472  (lo = bf16(f - hi))
//   W1T  @ 150994944  : 32,768      (256 n x 64 k bf16, hi)
//   W1L  @ 151027712  : 32,768      (lo part)
//   W2T  @ 151060480  : 131,072     (256 n x 256 k bf16)
//   total 151,191,552

using s16x8 = __attribute__((ext_vector_type(8))) short;
using f32x4 = __attribute__((ext_vector_type(4))) float;

__device__ __forceinline__ float bf2f(unsigned short u){
  return __uint_as_float(((unsigned)u) << 16);
}
__device__ __forceinline__ short f2bf(float f){
  unsigned b = __float_as_uint(f);
  return (short)((b + 0x7FFFu + ((b >> 16) & 1u)) >> 16);
}

// ---------------- prep: W1 -> 256x64 hi/lo bf16, W2 -> 256x256 bf16 ---------
__global__ void prep_kernel(const float* __restrict__ W1, const float* __restrict__ W2,
                            short* __restrict__ W1T, short* __restrict__ W1L,
                            short* __restrict__ W2T){
  const int n = threadIdx.x; // 0..255
  for(int k=0;k<64;k++){
    const float w = W1[(size_t)k*256 + n];
    const short h = f2bf(w);
    W1T[n*64 + k] = h;
    W1L[n*64 + k] = f2bf(w - bf2f((unsigned short)h));
  }
  for(int k=0;k<256;k++) W2T[n*256 + k] = f2bf(W2[(size_t)k*256 + n]);
}

// ---------------- conv3d 2->64, 3x3x3, SAME; writes hi/lo bf16 --------------
__global__ __launch_bounds__(256) void conv_kernel(
    const float* __restrict__ xr, const float* __restrict__ xi,
    const float* __restrict__ enc_w, const float* __restrict__ enc_b,
    short* __restrict__ fhi, short* __restrict__ flo)
{
  __shared__ __align__(16) float wl[64][56];
  __shared__ float bl[64];
  const int tid = threadIdx.x;
  for(int i=tid;i<3456;i+=256) wl[i/54][i%54] = enc_w[i];
  if(tid<128) wl[tid>>1][54+(tid&1)] = 0.f;
  if(tid<64)  bl[tid] = enc_b[tid];
  __syncthreads();

  const unsigned bi   = blockIdx.x;          // 2304 = 2*32*36
  const unsigned tile = bi % 36u;
  const unsigned t    = (bi/36u) % 32u;
  const unsigned b    = bi / 1152u;
  const int h = (int)((tile/6u)*16u) + (tid>>4);
  const int w = (int)((tile%6u)*16u) + (tid&15);

  float xv[56];
  xv[54]=0.f; xv[55]=0.f;
  int k=0;
  #pragma unroll
  for(int i=0;i<2;i++){
    const float* src = i ? xi : xr;
    #pragma unroll
    for(int dz=-1;dz<=1;dz++){
      const int tt = (int)t + dz;
      const bool tok = (tt>=0 && tt<32);
      const size_t tbase = (size_t)(b*32u + (unsigned)(tok?tt:0))*9216u;
      #pragma unroll
      for(int dy=-1;dy<=1;dy++){
        const int hh = h+dy;
        const bool hok = (hh>=0 && hh<96);
        #pragma unroll
        for(int dx=-1;dx<=1;dx++){
          const int ww = w+dx;
          const bool ok = tok && hok && (ww>=0 && ww<96);
          xv[k] = ok ? src[tbase + (size_t)(hh*96+ww)] : 0.f;
          k++;
        }
      }
    }
  }

  const unsigned idx = (b*32u+t)*9216u + (unsigned)(h*96+w);
  short* ph = fhi + (size_t)idx*64u;
  short* pl = flo + (size_t)idx*64u;
  #pragma unroll
  for(int g=0; g<4; g++){
    unsigned hw[8], lw[8];
    #pragma unroll
    for(int c2=0;c2<8;c2++){
      unsigned hpair=0, lpair=0;
      #pragma unroll
      for(int half=0; half<2; half++){
        const int c = g*16 + c2*2 + half;
        float acc = bl[c];
        const float4* wp = (const float4*)(&wl[c][0]);
        #pragma unroll
        for(int qq=0;qq<14;qq++){
          const float4 w4 = wp[qq];
          acc += w4.x*xv[qq*4+0] + w4.y*xv[qq*4+1]
               + w4.z*xv[qq*4+2] + w4.w*xv[qq*4+3];
        }
        const unsigned short hu = (unsigned short)f2bf(acc);
        const unsigned short lu = (unsigned short)f2bf(acc - bf2f(hu));
        hpair |= ((unsigned)hu) << (16*half);
        lpair |= ((unsigned)lu) << (16*half);
      }
      hw[c2]=hpair; lw[c2]=lpair;
    }
    uint4* dh = (uint4*)(ph + g*16);
    uint4* dl = (uint4*)(pl + g*16);
    dh[0] = make_uint4(hw[0],hw[1],hw[2],hw[3]);
    dh[1] = make_uint4(hw[4],hw[5],hw[6],hw[7]);
    dl[0] = make_uint4(lw[0],lw[1],lw[2],lw[3]);
    dl[1] = make_uint4(lw[4],lw[5],lw[6],lw[7]);
  }
}

// ---------------- fused SIREN MLP + lerp, MFMA 16x16x32 bf16 ----------------
// Block: 4 waves x 32 rows (evals). Eval = pixel*2 + {0=floor,1=ceil}; the
// floor/ceil pair are adjacent rows of the same wave -> lerp in epilogue.
__global__ __launch_bounds__(256) void mlp_kernel(
  const float* __restrict__ tcoord,
  const short* __restrict__ fhi, const short* __restrict__ flo,
  const short* __restrict__ W1T, const short* __restrict__ W1L,
  const float* __restrict__ W1,  const float* __restrict__ b1,
  const short* __restrict__ W2T, const float* __restrict__ b2,
  const float* __restrict__ W3,  const float* __restrict__ b3,
  float* __restrict__ out)
{
  __shared__ __align__(16) short hlds[4*32*256]; // 64 KB, per-wave 32x256 swizzled
  const int tid  = threadIdx.x;
  const int wave = tid>>6;
  const int lane = tid&63;
  const int q  = lane>>4;   // quad
  const int ln = lane&15;
  const unsigned evbase = blockIdx.x*128u + (unsigned)wave*32u;

  // ---- per-lane meta for row (lane&31) ----
  const unsigned rrow = (unsigned)(lane & 31);
  const unsigned ev = evbase + rrow;
  const unsigned pt = ev>>1;
  const unsigned fc = ev&1u;
  const unsigned wq = pt%96u;
  const unsigned hq = (pt/96u)%96u;
  const unsigned jq = (pt/9216u)%32u;
  const unsigned bq = pt/294912u;
  float tc = tcoord[bq*32u+jq];
  tc = fminf(fmaxf(tc, -1.0f), 1.0f - 1e-6f);
  const float dstep = 2.0f/31.0f;
  const int ti = (int)floorf((tc+1.0f)/dstep);
  const unsigned trow = (unsigned)ti + fc;       // <= 31
  const unsigned rowoff = (bq*32u+trow)*9216u + hq*96u + wq;

  const unsigned off0 = __shfl(rowoff, ln, 64);       // row ln
  const unsigned off1 = __shfl(rowoff, 16+ln, 64);    // row 16+ln
  float tcm[2][4];
  #pragma unroll
  for(int rt=0;rt<2;rt++)
    #pragma unroll
    for(int rr=0;rr<4;rr++)
      tcm[rt][rr] = __shfl(tc, rt*16 + q*4 + rr, 64);

  // ---- A1 fragments: A[m=ln][k=q*8+j], 2 ksteps, hi+lo ----
  s16x8 ahi[2][2], alo[2][2];
  {
    const size_t o0 = (size_t)off0*64u + (size_t)(q*8);
    const size_t o1 = (size_t)off1*64u + (size_t)(q*8);
    ahi[0][0] = *(const s16x8*)(fhi+o0);    ahi[0][1] = *(const s16x8*)(fhi+o0+32);
    ahi[1][0] = *(const s16x8*)(fhi+o1);    ahi[1][1] = *(const s16x8*)(fhi+o1+32);
    alo[0][0] = *(const s16x8*)(flo+o0);    alo[0][1] = *(const s16x8*)(flo+o0+32);
    alo[1][0] = *(const s16x8*)(flo+o1);    alo[1][1] = *(const s16x8*)(flo+o1+32);
  }

  short* myh = hlds + wave*(32*256);

  // ---- layer 1: h1 = sin(30*(F@W1[0:64] + tc*W1[64] + b1)) ----
  #pragma unroll 1
  for(int nt=0; nt<16; nt++){
    const int n = nt*16 + ln;
    const s16x8 bf0 = *(const s16x8*)(W1T + n*64 + q*8);
    const s16x8 bf1 = *(const s16x8*)(W1T + n*64 + 32 + q*8);
    const s16x8 bl0 = *(const s16x8*)(W1L + n*64 + q*8);
    const s16x8 bl1 = *(const s16x8*)(W1L + n*64 + 32 + q*8);
    const float w1l  = W1[(size_t)64*256 + n];
    const float bias = b1[n];
    const int g  = n>>3;
    const int ne = n&7;
    #pragma unroll
    for(int rt=0;rt<2;rt++){
      f32x4 acc = {0.f,0.f,0.f,0.f};
      acc = __builtin_amdgcn_mfma_f32_16x16x32_bf16(ahi[rt][0], bf0, acc, 0,0,0);
      acc = __builtin_amdgcn_mfma_f32_16x16x32_bf16(ahi[rt][1], bf1, acc, 0,0,0);
      acc = __builtin_amdgcn_mfma_f32_16x16x32_bf16(alo[rt][0], bf0, acc, 0,0,0);
      acc = __builtin_amdgcn_mfma_f32_16x16x32_bf16(alo[rt][1], bf1, acc, 0,0,0);
      acc = __builtin_amdgcn_mfma_f32_16x16x32_bf16(ahi[rt][0], bl0, acc, 0,0,0);
      acc = __builtin_amdgcn_mfma_f32_16x16x32_bf16(ahi[rt][1], bl1, acc, 0,0,0);
      #pragma unroll
      for(int rr=0;rr<4;rr++){
        const int m = rt*16 + q*4 + rr;            // D: row=q*4+reg, col=ln
        const float z = acc[rr] + tcm[rt][rr]*w1l + bias;
        // swizzled: element (m,n) at m*256 + ((n>>3)^(m&7))*8 + (n&7)
        myh[m*256 + ((g ^ (m&7))<<3) + ne] = f2bf(__sinf(30.0f*z));
      }
    }
  }

  __syncthreads();   // order layer-1 LDS writes before layer-2 LDS reads

  // ---- layer 2 (+3 folded): h2 = sin(30*(h1@W2+b2)); pred = h2@W3 ----
  float pacc[2][4];
  #pragma unroll
  for(int rt=0;rt<2;rt++)
    #pragma unroll
    for(int rr=0;rr<4;rr++) pacc[rt][rr]=0.f;

  #pragma unroll 1
  for(int cg=0; cg<4; cg++){
    f32x4 acc[2][4];
    const f32x4 zv = {0.f,0.f,0.f,0.f};
    #pragma unroll
    for(int rt=0;rt<2;rt++)
      #pragma unroll
      for(int nt=0;nt<4;nt++) acc[rt][nt] = zv;

    #pragma unroll
    for(int ks=0; ks<8; ks++){
      s16x8 a2[2];
      #pragma unroll
      for(int rt=0;rt<2;rt++){
        const int m  = rt*16 + ln;
        const int gk = ks*4 + q;
        a2[rt] = *(const s16x8*)(myh + m*256 + ((gk ^ (m&7))<<3));
      }
      s16x8 b2f[4];
      #pragma unroll
      for(int nt=0;nt<4;nt++){
        const int n = cg*64 + nt*16 + ln;
        b2f[nt] = *(const s16x8*)(W2T + n*256 + ks*32 + q*8);
      }
      #pragma unroll
      for(int rt=0;rt<2;rt++)
        #pragma unroll
        for(int nt=0;nt<4;nt++)
          acc[rt][nt] = __builtin_amdgcn_mfma_f32_16x16x32_bf16(a2[rt], b2f[nt], acc[rt][nt], 0,0,0);
    }
    #pragma unroll
    for(int nt=0;nt<4;nt++){
      const int n = cg*64 + nt*16 + ln;
      const float b2v = b2[n];
      const float w3v = W3[n];
      #pragma unroll
      for(int rt=0;rt<2;rt++)
        #pragma unroll
        for(int rr=0;rr<4;rr++){
          const float h2 = __sinf(30.0f*(acc[rt][nt][rr] + b2v));
          pacc[rt][rr] += h2*w3v;
        }
    }
  }

  // reduce over the 16 n-lanes (xor within ln bits keeps q fixed)
  #pragma unroll
  for(int rt=0;rt<2;rt++)
    #pragma unroll
    for(int rr=0;rr<4;rr++){
      float v = pacc[rt][rr];
      v += __shfl_xor(v, 1, 64);
      v += __shfl_xor(v, 2, 64);
      v += __shfl_xor(v, 4, 64);
      v += __shfl_xor(v, 8, 64);
      pacc[rt][rr] = v;
    }

  // ---- fused lerp: rows (2s, 2s+1) = (floor, ceil) of one pixel ----
  if(ln==0){
    const float b3v = b3[0];
    #pragma unroll
    for(int rt=0;rt<2;rt++){
      #pragma unroll
      for(int s=0;s<2;s++){
        const int m0 = rt*16 + q*4 + 2*s;
        const float tcp = tcm[rt][2*s];
        const int tip = (int)floorf((tcp+1.0f)/dstep);
        const float fci = (float)((double)tip*(2.0/31.0) - 1.0);
        const float tau = (tcp - fci)/dstep;
        const unsigned px = (evbase + (unsigned)m0)>>1;
        out[px] = pacc[rt][2*s]*(1.0f-tau) + pacc[rt][2*s+1]*tau + b3v;
      }
    }
  }
}

extern "C" void kernel_launch(void* const* d_in, const int* in_sizes, int n_in,
                              void* d_out, int out_size, void* d_ws, size_t ws_size,
                              hipStream_t stream){
  const float* xr     = (const float*)d_in[0];
  const float* xi     = (const float*)d_in[1];
  const float* tcoord = (const float*)d_in[2];
  const float* enc_w  = (const float*)d_in[3];
  const float* enc_b  = (const float*)d_in[4];
  const float* W1     = (const float*)d_in[5];
  const float* b1     = (const float*)d_in[6];
  const float* W2     = (const float*)d_in[7];
  const float* b2     = (const float*)d_in[8];
  const float* W3     = (const float*)d_in[9];
  const float* b3     = (const float*)d_in[10];

  char* ws = (char*)d_ws;
  short* fhi  = (short*)(ws);
  short* flo  = (short*)(ws + 75497472);
  short* W1T  = (short*)(ws + 150994944);
  short* W1L  = (short*)(ws + 151027712);
  short* W2T  = (short*)(ws + 151060480);
  float* out  = (float*)d_out;

  hipLaunchKernelGGL(prep_kernel, dim3(1),    dim3(256), 0, stream, W1, W2, W1T, W1L, W2T);
  hipLaunchKernelGGL(conv_kernel, dim3(2304), dim3(256), 0, stream, xr, xi, enc_w, enc_b, fhi, flo);
  hipLaunchKernelGGL(mlp_kernel,  dim3(9216), dim3(256), 0, stream, tcoord, fhi, flo,
                     W1T, W1L, W1, b1, W2T, b2, W3, b3, out);
}